// Round 10
// baseline (139.949 us; speedup 1.0000x reference)
//
#include <hip/hip_runtime.h>
#include <hip/hip_bf16.h>
#include <cstdint>
#include <cstddef>

typedef short bf16x8 __attribute__((ext_vector_type(8)));
typedef float f32x4 __attribute__((ext_vector_type(4)));
typedef unsigned short u16x8 __attribute__((ext_vector_type(8)));

#define DEV __device__ __forceinline__

DEV void gload16(const void* g, void* l) {
  __builtin_amdgcn_global_load_lds((const __attribute__((address_space(1))) void*)g,
                                   (__attribute__((address_space(3))) void*)l,
                                   16, 0, 0);
}

DEV unsigned short f2bf(float f) {
  __hip_bfloat16 h = __float2bfloat16(f);
  return *reinterpret_cast<unsigned short*>(&h);
}

DEV float b2f(unsigned short u) {
  union { float f; unsigned int i; } v;
  v.i = ((unsigned int)u) << 16;
  return v.f;
}

// ---- prep: Wvt[d][k] = sum_h WqkvV ; Wst[m][d] = sum_h Wout. One kernel, role by bid ----
__global__ __launch_bounds__(256) void k_prep(const float* __restrict__ Wqkv,
                                              const float* __restrict__ Wout,
                                              unsigned short* __restrict__ Wvt,
                                              unsigned short* __restrict__ Wst) {
  const int bid = blockIdx.x, t = threadIdx.x;
  if (bid < 1024) {
    int gid = bid * 256 + t;  // 2048 k x 128 d
    int k = gid >> 7, d = gid & 127;
    const float* p = Wqkv + (size_t)k * 6144 + 256 + d;
    float s = 0.f;
#pragma unroll
    for (int h = 0; h < 16; ++h) s += __builtin_nontemporal_load(p + h * 384);
    Wvt[(size_t)d * 2048 + k] = f2bf(s);
  } else {
    int gid = (bid - 1024) * 256 + t;  // 128 d x 2048 m
    int d = gid >> 11, m = gid & 2047;
    const float* p = Wout + (size_t)d * 2048 + m;
    float s = 0.f;
#pragma unroll
    for (int h = 0; h < 16; ++h) s += __builtin_nontemporal_load(p + h * 262144);
    Wst[(size_t)m * 128 + d] = f2bf(s);
  }
}

// ---- beff[m] = bout[m] + sum_d (sum_h bqkv[h][256+d]) * Ws[d][m] ----
__global__ __launch_bounds__(256) void k_beff(const float* __restrict__ bqkv,
                                              const unsigned short* __restrict__ Wst,
                                              const float* __restrict__ bout,
                                              float* __restrict__ be) {
  __shared__ float bv[128];
  int t = threadIdx.x;
  if (t < 128) {
    float s = 0.f;
#pragma unroll
    for (int h = 0; h < 16; ++h) s += bqkv[h * 384 + 256 + t];
    bv[t] = s;
  }
  __syncthreads();
  int m = blockIdx.x * 256 + t;  // grid 8
  float s = bout[m];
  const unsigned short* wr = Wst + (size_t)m * 128;
  for (int d = 0; d < 128; ++d) s = fmaf(bv[d], b2f(wr[d]), s);
  be[m] = s;
}

// ---- fused: Y = (X * Wvt^T) * Wst^T + beff ----
// 512 blocks x 256 thr (4 waves), m-tile 32.
// Phase 1 (= proven k_gemm1): T32 = X*Wvt^T, K=2048, B LDS-dbuf (swizzle both-sides),
//   A = NT fp32 loads + in-reg cvt, reg-dbuf. acc complete per wave (wn splits n, not K).
// T32[32][128] bf16 parks in LDS (swizzled). Phase 2: y32 = T32*Wst^T + be, K=128,
//   A-frags from T-LDS, B streamed from global (Wst 0.5 MB, L2/L1-hot), 4 n-slabs/wave.
__global__ __launch_bounds__(256, 2) void k_fused(const float* __restrict__ X,
                                                  const unsigned short* __restrict__ Wvt,
                                                  const unsigned short* __restrict__ Wst,
                                                  const float* __restrict__ be,
                                                  float* __restrict__ Y) {
  __shared__ char bs[2][16384];
  __shared__ char tls[8192];
  const int t = threadIdx.x, lane = t & 63, w = t >> 6;
  const int wm = w >> 1, wn = w & 1;
  const int l15 = lane & 15, l4 = lane >> 4;
  const int m0 = blockIdx.x * 32;

  int srow[4], scol[4];
#pragma unroll
  for (int c = 0; c < 4; ++c) {
    srow[c] = c * 32 + (t >> 3);
    scol[c] = ((t & 7) * 16) ^ ((srow[c] & 7) << 4);
  }
  const float* xrow = X + (size_t)(m0 + wm * 16 + l15) * 2048;

  f32x4 acc[4];
#pragma unroll
  for (int ni = 0; ni < 4; ++ni)
#pragma unroll
    for (int r = 0; r < 4; ++r) acc[ni][r] = 0.f;

#define STAGE1(kt2, q)                                                         \
  _Pragma("unroll") for (int c = 0; c < 4; ++c)                                \
      gload16((const char*)Wvt + (size_t)srow[c] * 4096 + (kt2) * 128 + scol[c],\
              bs[q] + c * 4096 + w * 1024);
#define ALOAD(ra, kt2)                                                         \
  _Pragma("unroll") for (int i = 0; i < 4; ++i)                                \
      ra[i] = __builtin_nontemporal_load(                                      \
          (const f32x4*)(xrow + (kt2) * 64 + (i >> 1) * 32 + l4 * 8 + (i & 1) * 4));
#define COMP1(q, ra)                                                           \
  do {                                                                         \
    bf16x8 af[2];                                                              \
    _Pragma("unroll") for (int ks = 0; ks < 2; ++ks) {                         \
      u16x8 u;                                                                 \
      _Pragma("unroll") for (int jj = 0; jj < 4; ++jj) {                       \
        u[jj] = f2bf(ra[ks * 2][jj]); u[jj + 4] = f2bf(ra[ks * 2 + 1][jj]);    \
      }                                                                        \
      af[ks] = (bf16x8)u;                                                      \
    }                                                                          \
    _Pragma("unroll") for (int ni = 0; ni < 4; ++ni)                           \
    _Pragma("unroll") for (int ks = 0; ks < 2; ++ks) {                         \
      int row = wn * 64 + ni * 16 + l15;                                       \
      int byt = (ks * 64 + l4 * 16) ^ ((row & 7) << 4);                        \
      bf16x8 bf = *(const bf16x8*)(bs[q] + row * 128 + byt);                   \
      acc[ni] = __builtin_amdgcn_mfma_f32_16x16x32_bf16(af[ks], bf, acc[ni], 0, 0, 0); \
    }                                                                          \
  } while (0)

  f32x4 raA[4], raB[4];
  STAGE1(0, 0) ALOAD(raA, 0)
  __syncthreads();
#pragma unroll 1
  for (int kt = 0; kt < 32; kt += 2) {
    STAGE1(kt + 1, 1) ALOAD(raB, kt + 1)
    COMP1(0, raA);
    __syncthreads();
    if (kt + 2 < 32) { STAGE1(kt + 2, 0) ALOAD(raA, kt + 2) }
    COMP1(1, raB);
    __syncthreads();
  }
#undef STAGE1
#undef ALOAD
#undef COMP1

  // park T in LDS (bf16, byte ^= (row&7)<<4 swizzle — matches phase-2 read)
#pragma unroll
  for (int ni = 0; ni < 4; ++ni)
#pragma unroll
    for (int r = 0; r < 4; ++r) {
      int row = wm * 16 + l4 * 4 + r;
      int colb = (wn * 64 + ni * 16 + l15) * 2;
      *(unsigned short*)(tls + row * 256 + (colb ^ ((row & 7) << 4))) = f2bf(acc[ni][r]);
    }
  __syncthreads();

  // ---- phase 2: K=128 sweep, B from global (L2-hot) ----
  bf16x8 af2[4];
#pragma unroll
  for (int kq = 0; kq < 4; ++kq) {
    int row = wm * 16 + l15;
    int byt = (kq * 64 + l4 * 16) ^ ((row & 7) << 4);
    af2[kq] = *(const bf16x8*)(tls + row * 256 + byt);
  }

#pragma unroll 1
  for (int i = 0; i < 4; ++i) {
    const int ns = wn + 2 * i;        // wave-parity slab split: waves share slabs pairwise
    const int n0 = ns * 256;
    f32x4 acc2[16];
#pragma unroll
    for (int nf = 0; nf < 16; ++nf)
#pragma unroll
      for (int r = 0; r < 4; ++r) acc2[nf][r] = 0.f;
#pragma unroll
    for (int nf = 0; nf < 16; ++nf) {
      const unsigned short* brow = Wst + (size_t)(n0 + nf * 16 + l15) * 128;
#pragma unroll
      for (int kq = 0; kq < 4; ++kq) {
        bf16x8 bf = *(const bf16x8*)(brow + kq * 32 + l4 * 8);
        acc2[nf] = __builtin_amdgcn_mfma_f32_16x16x32_bf16(af2[kq], bf, acc2[nf], 0, 0, 0);
      }
    }
#pragma unroll
    for (int nf = 0; nf < 16; ++nf) {
      int n = n0 + nf * 16 + l15;
      float bv = be[n];
#pragma unroll
      for (int r = 0; r < 4; ++r) {
        int row = m0 + wm * 16 + l4 * 4 + r;
        Y[(size_t)row * 2048 + n] = acc2[nf][r] + bv;
      }
    }
  }
}

extern "C" void kernel_launch(void* const* d_in, const int* in_sizes, int n_in,
                              void* d_out, int out_size, void* d_ws, size_t ws_size,
                              hipStream_t stream) {
  const float* x    = (const float*)d_in[0];
  const float* Wqkv = (const float*)d_in[1];
  const float* bqkv = (const float*)d_in[2];
  const float* Wout = (const float*)d_in[3];
  const float* bout = (const float*)d_in[4];
  float* y = (float*)d_out;

  char* ws = (char*)d_ws;
  unsigned short* Wvt  = (unsigned short*)(ws);             //   524,288 B  [128][2048] bf16
  unsigned short* Wst  = (unsigned short*)(ws + 524288);    //   524,288 B  [2048][128] bf16
  float*          beff = (float*)(ws + 1048576);            //     8,192 B

  k_prep<<<2048, 256, 0, stream>>>(Wqkv, Wout, Wvt, Wst);
  k_beff<<<8, 256, 0, stream>>>(bqkv, Wst, bout, beff);
  k_fused<<<512, 256, 0, stream>>>(x, Wvt, Wst, beff, y);
}